// Round 2
// baseline (788.317 us; speedup 1.0000x reference)
//
#include <hip/hip_runtime.h>
#include <cstdint>

typedef float f4 __attribute__((ext_vector_type(4)));

__device__ inline f4 f4_zero(){ f4 v = {0.f,0.f,0.f,0.f}; return v; }

// ---------- detect int64 vs int32 edge_index ----------
// If edge_index is int64 (values in [0,1e5)), every high 32-bit word is 0.
// If int32, odd 32-bit words are random indices — P(2048 zeros) ~ 0.
__global__ void k_detect(const uint32_t* __restrict__ p, int* __restrict__ flag){
    __shared__ int nz;
    if (threadIdx.x == 0) nz = 0;
    __syncthreads();
    int local = 0;
    for (int i = threadIdx.x; i < 2048; i += blockDim.x)
        if (p[2*i + 1] != 0u) local = 1;
    if (local) atomicOr(&nz, 1);
    __syncthreads();
    if (threadIdx.x == 0) *flag = (nz == 0) ? 1 : 0;   // 1 => int64
}

// ---------- convert indices to int32 + degree histogram ----------
__global__ void k_convert_hist(const void* __restrict__ eidx, int E,
                               const int* __restrict__ flag,
                               int* __restrict__ src32, int* __restrict__ dst32,
                               int* __restrict__ counts){
    int e = blockIdx.x * 256 + threadIdx.x;
    if (e >= E) return;
    int s, d;
    if (*flag) {
        const long long* p = (const long long*)eidx;
        s = (int)p[e];
        d = (int)p[(size_t)E + e];
    } else {
        const int* p = (const int*)eidx;
        s = p[e];
        d = p[E + e];
    }
    src32[e] = s;
    dst32[e] = d;
    atomicAdd(&counts[d], 1);
}

// ---------- single-block exclusive scan (rowptr) ----------
__global__ __launch_bounds__(1024) void k_scan(const int* __restrict__ counts, int n,
                                               int* __restrict__ rowptr){
    __shared__ int wsum[16];
    __shared__ int carry_s;
    int tid  = threadIdx.x;
    int lane = tid & 63;
    int wid  = tid >> 6;
    if (tid == 0){ carry_s = 0; rowptr[0] = 0; }
    __syncthreads();
    for (int base = 0; base < n; base += 1024){
        int i = base + tid;
        int v = (i < n) ? counts[i] : 0;
        int x = v;
        #pragma unroll
        for (int off = 1; off < 64; off <<= 1){
            int t = __shfl_up(x, off, 64);
            if (lane >= off) x += t;
        }
        if (lane == 63) wsum[wid] = x;
        __syncthreads();
        if (wid == 0 && lane < 16){
            int y = wsum[lane];
            #pragma unroll
            for (int off = 1; off < 16; off <<= 1){
                int t = __shfl_up(y, off, 64);
                if (lane >= off) y += t;
            }
            wsum[lane] = y;          // inclusive scan of wave sums
        }
        __syncthreads();
        int pre  = (wid > 0) ? wsum[wid - 1] : 0;
        int incl = carry_s + pre + x;
        if (i < n) rowptr[i + 1] = incl;
        __syncthreads();             // all reads of carry_s done
        if (tid == 1023) carry_s += wsum[15];
        __syncthreads();             // carry visible for next chunk
    }
}

// ---------- CSR bucket fill ----------
__global__ void k_fill(const int* __restrict__ src32, const int* __restrict__ dst32,
                       int E, int* __restrict__ cursor, int* __restrict__ esrc){
    int e = blockIdx.x * 256 + threadIdx.x;
    if (e >= E) return;
    int d = dst32[e];
    int pos = atomicAdd(&cursor[d], 1);
    esrc[pos] = src32[e];
}

// ---------- mean aggregation: one wave64 per dst node ----------
// lanes 0-31 take even edges, 32-63 odd edges; __shfl_xor(32) reduce at end.
// No intra-wave trip-count divergence (one node per wave).
__global__ __launch_bounds__(256) void k_aggregate(const float* __restrict__ feat,
                                                   const int* __restrict__ rowptr,
                                                   const int* __restrict__ esrc,
                                                   float* __restrict__ agg, int n){
    int wid  = threadIdx.x >> 6;            // 4 nodes per block
    int lane = threadIdx.x & 63;
    int half = lane >> 5;                   // 0 or 1
    int l    = lane & 31;                   // float4 index within row
    int node = blockIdx.x * 4 + wid;
    if (node >= n) return;
    const f4* feat4 = (const f4*)feat;
    int b = rowptr[node], e = rowptr[node + 1];
    f4 acc0 = f4_zero(), acc1 = f4_zero();
    int i = b + half;
    for (; i + 2 < e; i += 4){              // 4 rows (2 KB) in flight per wave
        int s0 = esrc[i], s1 = esrc[i + 2];
        acc0 += feat4[(size_t)s0 * 32 + l];
        acc1 += feat4[(size_t)s1 * 32 + l];
    }
    if (i < e) acc0 += feat4[(size_t)esrc[i] * 32 + l];
    f4 acc = acc0 + acc1;
    #pragma unroll
    for (int j = 0; j < 4; ++j)
        acc[j] += __shfl_xor(acc[j], 32, 64);
    int deg = e - b;
    float scale = 1.0f / (float)(deg > 1 ? deg : 1);
    if (half == 0)
        ((f4*)agg)[(size_t)node * 32 + l] = acc * scale;
}

// ---------- fused SAGE linear: out = relu(agg@Wl + bl + X@Wr) ----------
// One K=256 GEMM: A = [agg | X], B = [Wl ; Wr].
// 64 rows x 128 cols per block, 256 threads, 8x4 outputs per thread.
// NOTE: out may alias A2 — each block reads only its own 64 rows of A2,
// and all A2 reads (staging) complete before the epilogue writes those rows.
__global__ __launch_bounds__(256) void k_sage_gemm(
    const float* __restrict__ A1,   // agg  [M][128]
    const float* __restrict__ A2,   // x/h  [M][128]
    const float* __restrict__ Wl,   // [128][128] row-major
    const float* __restrict__ Wr,   // [128][128]
    const float* __restrict__ bias, // [128]
    float* __restrict__ out, int M)
{
    __shared__ __attribute__((aligned(16))) float Bs[64][128];
    __shared__ __attribute__((aligned(16))) float As[64][64];   // [k][row]
    int tid = threadIdx.x;
    int tx  = tid & 31;     // col quad  (cols tx*4 .. tx*4+3)
    int ty  = tid >> 5;     // row octet (rows ty*8 .. ty*8+7)
    int row0 = blockIdx.x * 64;

    float acc[8][4];
    #pragma unroll
    for (int i = 0; i < 8; ++i)
        #pragma unroll
        for (int j = 0; j < 4; ++j) acc[i][j] = 0.f;

    for (int ch = 0; ch < 4; ++ch){
        const float* Asrc = (ch < 2) ? A1 : A2;
        const float* Bsrc = (ch < 2) ? Wl : Wr;
        int kOff = (ch & 1) * 64;
        // stage B chunk [64k][128c] : 2048 float4, 8 per thread
        #pragma unroll
        for (int j = 0; j < 8; ++j){
            int f = tid + j * 256;
            int k = f >> 5, c4 = f & 31;
            f4 v = ((const f4*)Bsrc)[(size_t)(kOff + k) * 32 + c4];
            *((f4*)&Bs[k][c4 * 4]) = v;
        }
        // stage A chunk transposed [64k][64row] : 1024 float4, 4 per thread
        #pragma unroll
        for (int j = 0; j < 4; ++j){
            int f = tid + j * 256;
            int r = f & 63, kq = f >> 6;      // kq 0..15
            f4 v = f4_zero();
            if (row0 + r < M)
                v = ((const f4*)Asrc)[(size_t)(row0 + r) * 32 + (kOff >> 2) + kq];
            As[kq * 4 + 0][r] = v[0];
            As[kq * 4 + 1][r] = v[1];
            As[kq * 4 + 2][r] = v[2];
            As[kq * 4 + 3][r] = v[3];
        }
        __syncthreads();
        #pragma unroll 4
        for (int k = 0; k < 64; ++k){
            f4 b  = *((const f4*)&Bs[k][tx * 4]);
            f4 a0 = *((const f4*)&As[k][ty * 8]);
            f4 a1 = *((const f4*)&As[k][ty * 8 + 4]);
            #pragma unroll
            for (int i = 0; i < 4; ++i){
                #pragma unroll
                for (int j = 0; j < 4; ++j){
                    acc[i][j]     += a0[i] * b[j];
                    acc[i + 4][j] += a1[i] * b[j];
                }
            }
        }
        __syncthreads();
    }
    // epilogue: + bias, relu, store
    f4 bb = ((const f4*)bias)[tx];
    #pragma unroll
    for (int i = 0; i < 8; ++i){
        int r = row0 + ty * 8 + i;
        if (r < M){
            f4 v;
            #pragma unroll
            for (int j = 0; j < 4; ++j){
                float t = acc[i][j] + bb[j];
                v[j] = t > 0.f ? t : 0.f;
            }
            ((f4*)out)[(size_t)r * 32 + tx] = v;
        }
    }
}

extern "C" void kernel_launch(void* const* d_in, const int* in_sizes, int n_in,
                              void* d_out, int out_size, void* d_ws, size_t ws_size,
                              hipStream_t stream) {
    const float* x    = (const float*)d_in[0];
    const float* Wl1  = (const float*)d_in[1];
    const float* bl1  = (const float*)d_in[2];
    const float* Wr1  = (const float*)d_in[3];
    const float* Wl2  = (const float*)d_in[4];
    const float* bl2  = (const float*)d_in[5];
    const float* Wr2  = (const float*)d_in[6];
    const void*  eidx = d_in[7];
    float* out = (float*)d_out;

    const int N = in_sizes[0] / 128;
    const int E = in_sizes[7] / 2;

    char* ws = (char*)d_ws;
    size_t off = 0;
    auto alloc = [&](size_t bytes) -> void* {
        void* p = ws + off;
        off += (bytes + 255) & ~(size_t)255;
        return p;
    };
    int*   flag   = (int*)  alloc(4);
    int*   src32  = (int*)  alloc((size_t)E * 4);
    int*   dst32  = (int*)  alloc((size_t)E * 4);
    int*   counts = (int*)  alloc((size_t)N * 4);
    int*   rowptr = (int*)  alloc((size_t)(N + 1) * 4);
    int*   cursor = (int*)  alloc((size_t)N * 4);
    int*   esrc   = (int*)  alloc((size_t)E * 4);
    float* agg    = (float*)alloc((size_t)N * 128 * 4);
    float* h      = out;    // layer-1 output aliases d_out (safe, see k_sage_gemm)

    hipMemsetAsync(counts, 0, (size_t)N * 4, stream);
    k_detect<<<1, 256, 0, stream>>>((const uint32_t*)eidx, flag);
    k_convert_hist<<<(E + 255) / 256, 256, 0, stream>>>(eidx, E, flag, src32, dst32, counts);
    k_scan<<<1, 1024, 0, stream>>>(counts, N, rowptr);
    hipMemcpyAsync(cursor, rowptr, (size_t)N * 4, hipMemcpyDeviceToDevice, stream);
    k_fill<<<(E + 255) / 256, 256, 0, stream>>>(src32, dst32, E, cursor, esrc);

    // layer 1: h = relu(mean_agg(x) @ Wl1 + bl1 + x @ Wr1)
    k_aggregate<<<(N + 3) / 4, 256, 0, stream>>>(x, rowptr, esrc, agg, N);
    k_sage_gemm<<<(N + 63) / 64, 256, 0, stream>>>(agg, x, Wl1, Wr1, bl1, h, N);

    // layer 2: out = relu(mean_agg(h) @ Wl2 + bl2 + h @ Wr2)
    k_aggregate<<<(N + 3) / 4, 256, 0, stream>>>(h, rowptr, esrc, agg, N);
    k_sage_gemm<<<(N + 63) / 64, 256, 0, stream>>>(agg, h, Wl2, Wr2, bl2, out, N);
}